// Round 5
// baseline (394.577 us; speedup 1.0000x reference)
//
#include <hip/hip_runtime.h>
#include <hip/hip_bf16.h>

// ---------------------------------------------------------------------------
// NextTaskGAT: 2-layer GAT (H=4, C=64, F_IN=256) + FC(256->64).
// Pinned: inputs fp32 (bf16-grid), edge_index int32, dict order, OUTPUT FP32.
// R16 (= R15 resubmit; round-4 failure was container infra, kernel audited):
// GEMM 2-phase double-buffered pipeline (T3-minimum): raw s_barrier +
// counted vmcnt (never 0 mid-loop), prefetch next K-step before compute.
// 1-D grid + m204 bijective XCD-chunk swizzle (A-panel pair shares an XCD
// L2). cvt_all x-conversion vectorized x4. Gather = R11 form (best measured).
// ---------------------------------------------------------------------------

#define HEADS 4
#define FDIM  256

typedef __attribute__((ext_vector_type(4))) float f32x4;
typedef __attribute__((ext_vector_type(8))) short s16x8;

__device__ __forceinline__ void gload_lds16(const void* g, void* l) {
    __builtin_amdgcn_global_load_lds(
        (__attribute__((address_space(1))) void*)g,
        (__attribute__((address_space(3))) void*)l, 16, 0, 0);
}

__device__ __forceinline__ float b2f(unsigned short u) {
    return __uint_as_float((unsigned)u << 16);
}
__device__ __forceinline__ unsigned short f2b(float f) {
    __hip_bfloat16 b = __float2bfloat16(f);
    return *(unsigned short*)&b;
}

__device__ __forceinline__ float fast_exp2(float t) {
#if __has_builtin(__builtin_amdgcn_exp2f)
    return __builtin_amdgcn_exp2f(t);
#else
    return __expf(t * 0.6931471805599453f);
#endif
}

// ---------------------------------------------------------------------------
// Fused conversions + deg histogram: x->bf16 (x4 vec) | W1^T | W2^T | fcW^T
// | degree count. deg must be zeroed (hipMemsetAsync) BEFORE this kernel.
// ---------------------------------------------------------------------------
__global__ void cvt_all(const float* __restrict__ x, unsigned short* __restrict__ xb,
                        const float* __restrict__ W1, unsigned short* __restrict__ Wt1,
                        const float* __restrict__ W2, unsigned short* __restrict__ Wt2,
                        const float* __restrict__ fcW, unsigned short* __restrict__ fcWt,
                        const int* __restrict__ dstp, int* __restrict__ deg,
                        int nx4, int E, int Et) {
    int i = blockIdx.x * 256 + threadIdx.x;
    if (i < nx4) {                         // x: float4 -> ushort4 (bf16)
        float4 v = ((const float4*)x)[i];
        ushort4 o;
        o.x = f2b(v.x); o.y = f2b(v.y); o.z = f2b(v.z); o.w = f2b(v.w);
        ((ushort4*)xb)[i] = o;
        return;
    }
    i -= nx4;
    if (i < FDIM * FDIM) {                 // W1: [256][256] -> [c][r]
        int r = i >> 8, c = i & 255;
        Wt1[c * FDIM + r] = f2b(W1[i]);
        return;
    }
    i -= FDIM * FDIM;
    if (i < FDIM * FDIM) {
        int r = i >> 8, c = i & 255;
        Wt2[c * FDIM + r] = f2b(W2[i]);
        return;
    }
    i -= FDIM * FDIM;
    if (i < FDIM * 64) {                   // fcW: [256][64] -> [c][r]
        int r = i >> 6, c = i & 63;
        fcWt[c * FDIM + r] = f2b(fcW[i]);
        return;
    }
    i -= FDIM * 64;
    if (i < Et) {                          // degree histogram (incl self-loops)
        int dd = (i < E) ? dstp[i] : (i - E);
        atomicAdd(&deg[dd], 1);
    }
}

// ---------------------------------------------------------------------------
// GEMM: C[M][ncol] = A[M][256](bf16) x Bt[ncol][256]^T(bf16), +fp32 bias.
// BM=128, BK=64, 4 waves 2x2, XOR-swizzled 16B groups, global_load_lds.
// 2-phase double-buffered K-loop: stage(kt+1) issued BEFORE compute(kt);
// raw s_barrier + counted s_waitcnt vmcnt(SOPS) keeps prefetch in flight
// across barriers (a __syncthreads would drain vmcnt(0) and serialize).
// 1-D grid, m204 bijective XCD-chunk swizzle: the two y-halves of an
// A-panel are adjacent tile-ids -> same XCD chunk -> A re-read is L2-local.
// ATT: fused attention-coefficient epilogue, pre-scaled by log2(e).
// SCAT: blocks with bid >= nwg run the CSR edge-scatter instead.
// ---------------------------------------------------------------------------
template <int BN, bool F32OUT, bool ATT, bool SCAT>
__global__ __launch_bounds__(256, 2)
void gemm_bt_k256(const unsigned short* __restrict__ A,
                  const unsigned short* __restrict__ Bt,
                  void* __restrict__ C,
                  const float* __restrict__ bias,
                  const float* __restrict__ a_src,
                  const float* __restrict__ a_dst,
                  float* __restrict__ als,
                  float* __restrict__ ald,
                  int M, int ncol,
                  const int* __restrict__ sc_src,
                  const int* __restrict__ sc_dst,
                  int* __restrict__ cursor,
                  int* __restrict__ csrs,
                  int E, int n) {
    constexpr int BM = 128, BK = 64;
    constexpr int NFRAG = BN / 32;
    constexpr int BOPS = BN * 8 / 256;       // B-stage gloads per thread
    constexpr int SOPS = 4 + BOPS;           // gloads per stage per thread
    constexpr int YNUM = (BN == 128) ? 2 : 1;
    __shared__ __align__(16) unsigned short lA[2][BM * BK];
    __shared__ __align__(16) unsigned short lB[2][BN * BK];

    const int mb = (M + 127) >> 7;
    const int nwg = mb * YNUM;
    int bid = blockIdx.x;

    if constexpr (SCAT) {
        if (bid >= nwg) {
            int e = (bid - nwg) * 256 + (int)threadIdx.x;
            const int Et = E + n;
            if (e < Et) {
                int s, dd;
                if (e < E) { s = sc_src[e]; dd = sc_dst[e]; }
                else       { s = e - E;     dd = s; }
                int p = atomicAdd(&cursor[dd], 1);
                csrs[p] = s;
            }
            return;
        }
    }

    // m204 bijective XCD-chunk swizzle (8 XCDs)
    {
        const int q = nwg >> 3, r = nwg & 7;
        const int xcd = bid & 7, sub = bid >> 3;
        bid = (xcd < r ? xcd * (q + 1) : r * (q + 1) + (xcd - r) * q) + sub;
    }
    const int gy = (YNUM == 2) ? (bid & 1) : 0;
    const int gx = (YNUM == 2) ? (bid >> 1) : bid;

    const int tid  = threadIdx.x;
    const int lane = tid & 63;
    const int wave = tid >> 6;
    const int wm = wave & 1, wn = wave >> 1;
    const int m0 = gx * BM;
    const int n0 = gy * BN;
    const int quad = lane >> 4, col16 = lane & 15;

    f32x4 acc[4][NFRAG];
#pragma unroll
    for (int i = 0; i < 4; ++i)
#pragma unroll
        for (int j = 0; j < NFRAG; ++j) acc[i][j] = (f32x4){0.f, 0.f, 0.f, 0.f};

    auto stage = [&](int kt, int buf) {
        const int k0 = kt * BK;
#pragma unroll
        for (int i = 0; i < 4; ++i) {
            int slot = tid + i * 256;
            int row = slot >> 3, g = slot & 7;
            int gs = g ^ (row & 7);
            int rg = m0 + row; rg = rg < M ? rg : (M - 1);
            gload_lds16(A + (size_t)rg * FDIM + k0 + gs * 8,
                        (char*)lA[buf] + (size_t)slot * 16);
        }
#pragma unroll
        for (int i = 0; i < BOPS; ++i) {
            int slot = tid + i * 256;
            int row = slot >> 3, g = slot & 7;
            int gs = g ^ (row & 7);
            gload_lds16(Bt + (size_t)(n0 + row) * FDIM + k0 + gs * 8,
                        (char*)lB[buf] + (size_t)slot * 16);
        }
    };

    stage(0, 0);

#pragma unroll 1
    for (int kt = 0; kt < 4; ++kt) {
        const int cur = kt & 1;
        if (kt < 3) {
            stage(kt + 1, cur ^ 1);
            asm volatile("s_waitcnt vmcnt(%0)" :: "i"(SOPS) : "memory");
        } else {
            asm volatile("s_waitcnt vmcnt(0)" ::: "memory");
        }
        __builtin_amdgcn_sched_barrier(0);
        __builtin_amdgcn_s_barrier();
        __builtin_amdgcn_sched_barrier(0);

#pragma unroll
        for (int kk = 0; kk < 2; ++kk) {
            const int kg = kk * 4 + quad;
            s16x8 af[4], bfr[NFRAG];
#pragma unroll
            for (int i = 0; i < 4; ++i) {
                int row = wm * 64 + i * 16 + col16;
                int g = kg ^ (row & 7);
                af[i] = *(const s16x8*)((const char*)lA[cur] + (size_t)(row * 8 + g) * 16);
            }
#pragma unroll
            for (int j = 0; j < NFRAG; ++j) {
                int row = wn * (BN / 2) + j * 16 + col16;
                int g = kg ^ (row & 7);
                bfr[j] = *(const s16x8*)((const char*)lB[cur] + (size_t)(row * 8 + g) * 16);
            }
#pragma unroll
            for (int i = 0; i < 4; ++i)
#pragma unroll
                for (int j = 0; j < NFRAG; ++j)
                    acc[i][j] = __builtin_amdgcn_mfma_f32_16x16x32_bf16(
                        af[i], bfr[j], acc[i][j], 0, 0, 0);
        }

        __builtin_amdgcn_sched_barrier(0);
        __builtin_amdgcn_s_barrier();
        __builtin_amdgcn_sched_barrier(0);
    }

    // C epilogue: D row = quad*4 + r, col = lane&15 (m89-verified layout)
#pragma unroll
    for (int i = 0; i < 4; ++i) {
#pragma unroll
        for (int j = 0; j < NFRAG; ++j) {
#pragma unroll
            for (int r = 0; r < 4; ++r) {
                int row = m0 + wm * 64 + i * 16 + quad * 4 + r;
                int col = n0 + wn * (BN / 2) + j * 16 + col16;
                if (row < M) {
                    float v = acc[i][j][r];
                    if (bias) v += bias[col];
                    if constexpr (F32OUT)
                        ((float*)C)[(size_t)row * ncol + col] = v;
                    else
                        ((unsigned short*)C)[(size_t)row * ncol + col] = f2b(v);
                }
            }
        }
    }

    if constexpr (ATT) {
        constexpr float LOG2E = 1.4426950408889634f;
        const int head = gy * 2 + wn;
        float asv[4], adv[4];
#pragma unroll
        for (int j = 0; j < 4; ++j) {
            int c = head * 64 + j * 16 + col16;
            asv[j] = a_src[c] * LOG2E;
            adv[j] = a_dst[c] * LOG2E;
        }
#pragma unroll
        for (int i = 0; i < 4; ++i) {
#pragma unroll
            for (int r = 0; r < 4; ++r) {
                float vs = acc[i][0][r] * asv[0] + acc[i][1][r] * asv[1]
                         + acc[i][2][r] * asv[2] + acc[i][3][r] * asv[3];
                float vd = acc[i][0][r] * adv[0] + acc[i][1][r] * adv[1]
                         + acc[i][2][r] * adv[2] + acc[i][3][r] * adv[3];
#pragma unroll
                for (int m = 1; m < 16; m <<= 1) {
                    vs += __shfl_xor(vs, m, 16);
                    vd += __shfl_xor(vd, m, 16);
                }
                int row = m0 + wm * 64 + i * 16 + quad * 4 + r;
                if (col16 == 0 && row < M) {
                    als[row * HEADS + head] = vs;
                    ald[row * HEADS + head] = vd;
                }
            }
        }
    }
}

// ---------------------------------------------------------------------------
// CSR prefix scan: each block brute-force sums deg[0 .. b*256) (vectorized,
// ~20 MB total extra reads), then scans its own 256 chunk. No ordering deps.
// ---------------------------------------------------------------------------
__global__ void csr_scan(const int* __restrict__ deg, int* __restrict__ offs,
                         int* __restrict__ cursor, int n) {
    __shared__ int red[4];
    __shared__ int wsums[4];
    __shared__ int base_sh;
    const int tid = threadIdx.x, lane = tid & 63, wv = tid >> 6;
    const int start = blockIdx.x * 256;

    // 1) base = sum deg[0..start)
    int base = 0;
    for (int i = tid * 4; i < start; i += 1024) {
        int4 v = *(const int4*)(deg + i);     // start % 256 == 0 -> aligned
        base += v.x + v.y + v.z + v.w;
    }
#pragma unroll
    for (int m = 1; m < 64; m <<= 1) base += __shfl_xor(base, m, 64);
    if (lane == 0) red[wv] = base;
    __syncthreads();
    if (tid == 0) base_sh = red[0] + red[1] + red[2] + red[3];

    // 2) scan own chunk
    const int i = start + tid;
    int v = (i < n) ? deg[i] : 0;
    int acc = v;
#pragma unroll
    for (int d = 1; d < 64; d <<= 1) {
        int t = __shfl_up(acc, d, 64);
        if (lane >= d) acc += t;
    }
    if (lane == 63) wsums[wv] = acc;
    __syncthreads();
    int wo = 0;
#pragma unroll
    for (int k = 0; k < 4; ++k) wo += (k < wv) ? wsums[k] : 0;
    if (i < n) {
        int o = base_sh + wo + acc - v;
        offs[i] = o;
        cursor[i] = o;
    }
}

// ---------------------------------------------------------------------------
// Fused gather (R11 form: one wave per dst node, 4 ch/lane, 8x unroll; 8
// rows of h in flight). als/ald arrive pre-scaled by log2(e) -> bare exp2.
// ---------------------------------------------------------------------------
__global__ void gat_gather(const int* __restrict__ off,
                           const int* __restrict__ deg,
                           const int* __restrict__ csr_src,
                           const float* __restrict__ als,
                           const float* __restrict__ ald,
                           const unsigned short* __restrict__ h,
                           const float* __restrict__ bias,
                           unsigned short* __restrict__ x2, int n) {
    const int lane = threadIdx.x & 63;
    const int d = (blockIdx.x * blockDim.x + threadIdx.x) >> 6;
    if (d >= n) return;
    const int head = lane >> 4;
    const float aldh = ald[4 * d + head];
    const int start = off[d];
    const int end = start + deg[d];

    float a0 = 0.f, a1 = 0.f, a2 = 0.f, a3 = 0.f, den = 0.f;
    int j = start;
    for (; j + 8 <= end; j += 8) {
        int s[8];
#pragma unroll
        for (int u = 0; u < 8; ++u) s[u] = csr_src[j + u];
        float e[8];
#pragma unroll
        for (int u = 0; u < 8; ++u) e[u] = als[4 * s[u] + head];
        ushort4 hv[8];
#pragma unroll
        for (int u = 0; u < 8; ++u)
            hv[u] = *(const ushort4*)(h + (size_t)s[u] * FDIM + lane * 4);
#pragma unroll
        for (int u = 0; u < 8; ++u) {
            float t = e[u] + aldh;
            t = t > 0.f ? t : 0.2f * t;
            float w = fast_exp2(t);
            den += w;
            a0 += w * b2f(hv[u].x);
            a1 += w * b2f(hv[u].y);
            a2 += w * b2f(hv[u].z);
            a3 += w * b2f(hv[u].w);
        }
    }
    for (; j + 4 <= end; j += 4) {
        int s[4];
#pragma unroll
        for (int u = 0; u < 4; ++u) s[u] = csr_src[j + u];
        float e[4];
#pragma unroll
        for (int u = 0; u < 4; ++u) e[u] = als[4 * s[u] + head];
        ushort4 hv[4];
#pragma unroll
        for (int u = 0; u < 4; ++u)
            hv[u] = *(const ushort4*)(h + (size_t)s[u] * FDIM + lane * 4);
#pragma unroll
        for (int u = 0; u < 4; ++u) {
            float t = e[u] + aldh;
            t = t > 0.f ? t : 0.2f * t;
            float w = fast_exp2(t);
            den += w;
            a0 += w * b2f(hv[u].x);
            a1 += w * b2f(hv[u].y);
            a2 += w * b2f(hv[u].z);
            a3 += w * b2f(hv[u].w);
        }
    }
    for (; j < end; ++j) {
        int s = csr_src[j];
        float t = als[4 * s + head] + aldh;
        t = t > 0.f ? t : 0.2f * t;
        float w = fast_exp2(t);
        ushort4 hv = *(const ushort4*)(h + (size_t)s * FDIM + lane * 4);
        den += w;
        a0 += w * b2f(hv.x);
        a1 += w * b2f(hv.y);
        a2 += w * b2f(hv.z);
        a3 += w * b2f(hv.w);
    }
    const float inv = 1.0f / den;
    const int c = lane * 4;
    float v0 = a0 * inv + bias[c + 0];
    float v1 = a1 * inv + bias[c + 1];
    float v2 = a2 * inv + bias[c + 2];
    float v3 = a3 * inv + bias[c + 3];
    v0 = v0 > 0.f ? v0 : expm1f(v0);
    v1 = v1 > 0.f ? v1 : expm1f(v1);
    v2 = v2 > 0.f ? v2 : expm1f(v2);
    v3 = v3 > 0.f ? v3 : expm1f(v3);
    ushort4 o;
    o.x = f2b(v0); o.y = f2b(v1); o.z = f2b(v2); o.w = f2b(v3);
    *(ushort4*)(x2 + (size_t)d * FDIM + c) = o;
}

// ---------------------------------------------------------------------------
extern "C" void kernel_launch(void* const* d_in, const int* in_sizes, int n_in,
                              void* d_out, int out_size, void* d_ws, size_t ws_size,
                              hipStream_t stream) {
    const float* x   = (const float*)d_in[0];
    const int*   ei  = (const int*)d_in[1];
    const float* W1  = (const float*)d_in[3];
    const float* as1 = (const float*)d_in[4];
    const float* ad1 = (const float*)d_in[5];
    const float* b1  = (const float*)d_in[6];
    const float* W2  = (const float*)d_in[7];
    const float* as2 = (const float*)d_in[8];
    const float* ad2 = (const float*)d_in[9];
    const float* b2  = (const float*)d_in[10];
    const float* fcW = (const float*)d_in[11];
    const float* fcb = (const float*)d_in[12];
    float* out = (float*)d_out;

    const int n = in_sizes[0] / FDIM;   // 50000
    const int E = in_sizes[1] / 2;      // 800000
    const int Etot = E + n;
    const int* srcp = ei;
    const int* dstp = ei + E;
    const int nb = (n + 255) / 256;

    // -------- workspace carve (256B aligned), ~57 MB --------
    char* ws = (char*)d_ws;
    size_t off_b = 0;
    auto carve = [&](size_t bytes) -> char* {
        char* p = ws + off_b;
        off_b += (bytes + 255) & ~(size_t)255;
        return p;
    };
    unsigned short* xb = (unsigned short*)carve((size_t)n * FDIM * 2);  // also x2
    unsigned short* h  = (unsigned short*)carve((size_t)n * FDIM * 2);
    float* als  = (float*)carve((size_t)n * HEADS * 4);
    float* ald  = (float*)carve((size_t)n * HEADS * 4);
    int* deg    = (int*)carve((size_t)n * 4);
    int* offs   = (int*)carve((size_t)(n + 1) * 4);
    int* cursor = (int*)carve((size_t)n * 4);
    int* csr_src = (int*)carve((size_t)Etot * 4);
    unsigned short* Wt1  = (unsigned short*)carve(FDIM * FDIM * 2);
    unsigned short* Wt2  = (unsigned short*)carve(FDIM * FDIM * 2);
    unsigned short* fcWt = (unsigned short*)carve(64 * FDIM * 2);
    unsigned short* x2 = xb;   // alias: xb dead after layer-1 GEMM

    const int mblocks = (n + 127) / 128;
    const int nx4 = n * FDIM / 4;
    const int cvt_total = nx4 + 2 * FDIM * FDIM + FDIM * 64 + Etot;
    const int SB = (Etot + 255) / 256;   // scatter blocks

    // -------- zero deg (stream op; capture-legal) --------
    hipMemsetAsync(deg, 0, (size_t)n * 4, stream);

    // -------- fused conversions + degree histogram --------
    cvt_all<<<(cvt_total + 255) / 256, 256, 0, stream>>>(
        x, xb, W1, Wt1, W2, Wt2, fcW, fcWt, dstp, deg, nx4, E, Etot);

    // -------- CSR offsets --------
    csr_scan<<<nb, 256, 0, stream>>>(deg, offs, cursor, n);

    // -------- layer 1 GEMM + fused att coef + fused edge scatter --------
    gemm_bt_k256<128, false, true, true><<<mblocks * 2 + SB, 256, 0, stream>>>(
        xb, Wt1, h, nullptr, as1, ad1, als, ald, n, FDIM,
        srcp, dstp, cursor, csr_src, E, n);
    gat_gather<<<(n + 3) / 4, 256, 0, stream>>>(
        offs, deg, csr_src, als, ald, h, b1, x2, n);

    // -------- layer 2 --------
    gemm_bt_k256<128, false, true, false><<<mblocks * 2, 256, 0, stream>>>(
        x2, Wt2, h, nullptr, as2, ad2, als, ald, n, FDIM,
        nullptr, nullptr, nullptr, nullptr, 0, 0);
    gat_gather<<<(n + 3) / 4, 256, 0, stream>>>(
        offs, deg, csr_src, als, ald, h, b2, x2, n);

    // -------- final FC: out[n][64] = x2 @ fcW + fcb (FP32 out) --------
    gemm_bt_k256<64, true, false, false><<<mblocks, 256, 0, stream>>>(
        x2, fcWt, out, fcb, nullptr, nullptr, nullptr, nullptr, n, 64,
        nullptr, nullptr, nullptr, nullptr, 0, 0);
}

// Round 6
// 376.235 us; speedup vs baseline: 1.0488x; 1.0488x over previous
//
#include <hip/hip_runtime.h>
#include <hip/hip_bf16.h>

// ---------------------------------------------------------------------------
// NextTaskGAT: 2-layer GAT (H=4, C=64, F_IN=256) + FC(256->64).
// Pinned: inputs fp32 (bf16-grid), edge_index int32, dict order, OUTPUT FP32.
// R17: GEMM reverted to R14 single-buffer K-loop (R16's 64KB dbuf halved
// occupancy to 2 blocks/CU -> 80us, MfmaUtil 3%; occupancy > pipeline at
// K=256). Kept: 1-D grid + m204 XCD swizzle, vec-x4 cvt, exp2-folded att.
// New: deg histogram split to own tiny kernel; csr_scan folded into the
// convert dispatch as extra blocks (memset + 7 kernels total).
// ---------------------------------------------------------------------------

#define HEADS 4
#define FDIM  256

typedef __attribute__((ext_vector_type(4))) float f32x4;
typedef __attribute__((ext_vector_type(8))) short s16x8;

__device__ __forceinline__ void gload_lds16(const void* g, void* l) {
    __builtin_amdgcn_global_load_lds(
        (__attribute__((address_space(1))) void*)g,
        (__attribute__((address_space(3))) void*)l, 16, 0, 0);
}

__device__ __forceinline__ float b2f(unsigned short u) {
    return __uint_as_float((unsigned)u << 16);
}
__device__ __forceinline__ unsigned short f2b(float f) {
    __hip_bfloat16 b = __float2bfloat16(f);
    return *(unsigned short*)&b;
}

__device__ __forceinline__ float fast_exp2(float t) {
#if __has_builtin(__builtin_amdgcn_exp2f)
    return __builtin_amdgcn_exp2f(t);
#else
    return __expf(t * 0.6931471805599453f);
#endif
}

// ---------------------------------------------------------------------------
// Degree histogram (incl self-loops). deg zeroed by hipMemsetAsync before.
// ---------------------------------------------------------------------------
__global__ void deg_hist(const int* __restrict__ dstp, int* __restrict__ deg,
                         int E, int Et) {
    int e = blockIdx.x * 256 + threadIdx.x;
    if (e >= Et) return;
    int dd = (e < E) ? dstp[e] : (e - E);
    atomicAdd(&deg[dd], 1);
}

// ---------------------------------------------------------------------------
// Fused conversions + CSR prefix scan in ONE dispatch.
// Blocks [0, cvtblocks): x->bf16 (x4 vec) | W1^T | W2^T | fcW^T.
// Blocks [cvtblocks, ...): csr_scan (deg complete from prior dispatch).
// Scan: each scan-block brute-force sums deg[0 .. sid*256) (vectorized),
// then scans its own 256 chunk. No cross-block ordering needed.
// ---------------------------------------------------------------------------
__global__ void cvt_scan(const float* __restrict__ x, unsigned short* __restrict__ xb,
                         const float* __restrict__ W1, unsigned short* __restrict__ Wt1,
                         const float* __restrict__ W2, unsigned short* __restrict__ Wt2,
                         const float* __restrict__ fcW, unsigned short* __restrict__ fcWt,
                         const int* __restrict__ deg, int* __restrict__ offs,
                         int* __restrict__ cursor,
                         int nx4, int n, int cvtblocks) {
    if ((int)blockIdx.x >= cvtblocks) {
        // ---- scan part ----
        __shared__ int red[4];
        __shared__ int wsums[4];
        __shared__ int base_sh;
        const int tid = threadIdx.x, lane = tid & 63, wv = tid >> 6;
        const int sid = (int)blockIdx.x - cvtblocks;
        const int start = sid * 256;

        int base = 0;
        for (int i = tid * 4; i < start; i += 1024) {
            int4 v = *(const int4*)(deg + i);   // start % 256 == 0 -> aligned
            base += v.x + v.y + v.z + v.w;
        }
#pragma unroll
        for (int m = 1; m < 64; m <<= 1) base += __shfl_xor(base, m, 64);
        if (lane == 0) red[wv] = base;
        __syncthreads();
        if (tid == 0) base_sh = red[0] + red[1] + red[2] + red[3];

        const int i = start + tid;
        int v = (i < n) ? deg[i] : 0;
        int acc = v;
#pragma unroll
        for (int d = 1; d < 64; d <<= 1) {
            int t = __shfl_up(acc, d, 64);
            if (lane >= d) acc += t;
        }
        if (lane == 63) wsums[wv] = acc;
        __syncthreads();
        int wo = 0;
#pragma unroll
        for (int k = 0; k < 4; ++k) wo += (k < wv) ? wsums[k] : 0;
        if (i < n) {
            int o = base_sh + wo + acc - v;
            offs[i] = o;
            cursor[i] = o;
        }
        return;
    }

    // ---- convert part ----
    int i = blockIdx.x * 256 + threadIdx.x;
    if (i < nx4) {                         // x: float4 -> ushort4 (bf16)
        float4 v = ((const float4*)x)[i];
        ushort4 o;
        o.x = f2b(v.x); o.y = f2b(v.y); o.z = f2b(v.z); o.w = f2b(v.w);
        ((ushort4*)xb)[i] = o;
        return;
    }
    i -= nx4;
    if (i < FDIM * FDIM) {                 // W1: [256][256] -> [c][r]
        int r = i >> 8, c = i & 255;
        Wt1[c * FDIM + r] = f2b(W1[i]);
        return;
    }
    i -= FDIM * FDIM;
    if (i < FDIM * FDIM) {
        int r = i >> 8, c = i & 255;
        Wt2[c * FDIM + r] = f2b(W2[i]);
        return;
    }
    i -= FDIM * FDIM;
    if (i < FDIM * 64) {                   // fcW: [256][64] -> [c][r]
        int r = i >> 6, c = i & 63;
        fcWt[c * FDIM + r] = f2b(fcW[i]);
    }
}

// ---------------------------------------------------------------------------
// GEMM: C[M][ncol] = A[M][256](bf16) x Bt[ncol][256]^T(bf16), +fp32 bias.
// BM=128, BK=64, 4 waves 2x2, XOR-swizzled 16B groups, global_load_lds.
// Single-buffer K-loop (R14 form): 32KB LDS -> ~5 blocks/CU; at K=256
// (4 K-steps) occupancy beats pipelining (R16 measured: dbuf 64KB -> 2
// blocks/CU -> 80us, MfmaUtil 3%).
// 1-D grid, m204 bijective XCD-chunk swizzle: the two y-halves of an
// A-panel are adjacent tile-ids -> same XCD chunk -> A re-read is L2-local.
// ATT: fused attention-coefficient epilogue, pre-scaled by log2(e) so the
// gather kernel can use a bare v_exp_f32 (exp2); exp(leaky(x)) ==
// exp2(leaky(x*log2e)) exactly (leaky_relu is positively homogeneous).
// SCAT: blocks with bid >= nwg run the CSR edge-scatter instead.
// ---------------------------------------------------------------------------
template <int BN, bool F32OUT, bool ATT, bool SCAT>
__global__ __launch_bounds__(256, 2)
void gemm_bt_k256(const unsigned short* __restrict__ A,
                  const unsigned short* __restrict__ Bt,
                  void* __restrict__ C,
                  const float* __restrict__ bias,
                  const float* __restrict__ a_src,
                  const float* __restrict__ a_dst,
                  float* __restrict__ als,
                  float* __restrict__ ald,
                  int M, int ncol,
                  const int* __restrict__ sc_src,
                  const int* __restrict__ sc_dst,
                  int* __restrict__ cursor,
                  int* __restrict__ csrs,
                  int E, int n) {
    constexpr int BM = 128, BK = 64;
    constexpr int NFRAG = BN / 32;
    constexpr int YNUM = (BN == 128) ? 2 : 1;
    __shared__ __align__(16) unsigned short lA[BM * BK];
    __shared__ __align__(16) unsigned short lB[BN * BK];

    const int mb = (M + 127) >> 7;
    const int nwg = mb * YNUM;
    int bid = blockIdx.x;

    if constexpr (SCAT) {
        if (bid >= nwg) {
            int e = (bid - nwg) * 256 + (int)threadIdx.x;
            const int Et = E + n;
            if (e < Et) {
                int s, dd;
                if (e < E) { s = sc_src[e]; dd = sc_dst[e]; }
                else       { s = e - E;     dd = s; }
                int p = atomicAdd(&cursor[dd], 1);
                csrs[p] = s;
            }
            return;
        }
    }

    // m204 bijective XCD-chunk swizzle (8 XCDs)
    {
        const int q = nwg >> 3, r = nwg & 7;
        const int xcd = bid & 7, sub = bid >> 3;
        bid = (xcd < r ? xcd * (q + 1) : r * (q + 1) + (xcd - r) * q) + sub;
    }
    const int gy = (YNUM == 2) ? (bid & 1) : 0;
    const int gx = (YNUM == 2) ? (bid >> 1) : bid;

    const int tid  = threadIdx.x;
    const int lane = tid & 63;
    const int wave = tid >> 6;
    const int wm = wave & 1, wn = wave >> 1;
    const int m0 = gx * BM;
    const int n0 = gy * BN;
    const int quad = lane >> 4, col16 = lane & 15;

    f32x4 acc[4][NFRAG];
#pragma unroll
    for (int i = 0; i < 4; ++i)
#pragma unroll
        for (int j = 0; j < NFRAG; ++j) acc[i][j] = (f32x4){0.f, 0.f, 0.f, 0.f};

#pragma unroll 1
    for (int kt = 0; kt < 4; ++kt) {
        const int k0 = kt * BK;
#pragma unroll
        for (int i = 0; i < 4; ++i) {
            int slot = tid + i * 256;
            int row = slot >> 3, g = slot & 7;
            int gs = g ^ (row & 7);
            int rg = m0 + row; rg = rg < M ? rg : (M - 1);
            gload_lds16(A + (size_t)rg * FDIM + k0 + gs * 8,
                        (char*)lA + (size_t)slot * 16);
        }
#pragma unroll
        for (int i = 0; i < BN * 8 / 256; ++i) {
            int slot = tid + i * 256;
            int row = slot >> 3, g = slot & 7;
            int gs = g ^ (row & 7);
            gload_lds16(Bt + (size_t)(n0 + row) * FDIM + k0 + gs * 8,
                        (char*)lB + (size_t)slot * 16);
        }
        __syncthreads();

#pragma unroll
        for (int kk = 0; kk < 2; ++kk) {
            const int kg = kk * 4 + quad;
            s16x8 af[4], bfr[NFRAG];
#pragma unroll
            for (int i = 0; i < 4; ++i) {
                int row = wm * 64 + i * 16 + col16;
                int g = kg ^ (row & 7);
                af[i] = *(const s16x8*)((const char*)lA + (size_t)(row * 8 + g) * 16);
            }
#pragma unroll
            for (int j = 0; j < NFRAG; ++j) {
                int row = wn * (BN / 2) + j * 16 + col16;
                int g = kg ^ (row & 7);
                bfr[j] = *(const s16x8*)((const char*)lB + (size_t)(row * 8 + g) * 16);
            }
#pragma unroll
            for (int i = 0; i < 4; ++i)
#pragma unroll
                for (int j = 0; j < NFRAG; ++j)
                    acc[i][j] = __builtin_amdgcn_mfma_f32_16x16x32_bf16(
                        af[i], bfr[j], acc[i][j], 0, 0, 0);
        }
        __syncthreads();
    }

    // C epilogue: D row = quad*4 + r, col = lane&15 (m89-verified layout)
#pragma unroll
    for (int i = 0; i < 4; ++i) {
#pragma unroll
        for (int j = 0; j < NFRAG; ++j) {
#pragma unroll
            for (int r = 0; r < 4; ++r) {
                int row = m0 + wm * 64 + i * 16 + quad * 4 + r;
                int col = n0 + wn * (BN / 2) + j * 16 + col16;
                if (row < M) {
                    float v = acc[i][j][r];
                    if (bias) v += bias[col];
                    if constexpr (F32OUT)
                        ((float*)C)[(size_t)row * ncol + col] = v;
                    else
                        ((unsigned short*)C)[(size_t)row * ncol + col] = f2b(v);
                }
            }
        }
    }

    if constexpr (ATT) {
        constexpr float LOG2E = 1.4426950408889634f;
        const int head = gy * 2 + wn;
        float asv[4], adv[4];
#pragma unroll
        for (int j = 0; j < 4; ++j) {
            int c = head * 64 + j * 16 + col16;
            asv[j] = a_src[c] * LOG2E;
            adv[j] = a_dst[c] * LOG2E;
        }
#pragma unroll
        for (int i = 0; i < 4; ++i) {
#pragma unroll
            for (int r = 0; r < 4; ++r) {
                float vs = acc[i][0][r] * asv[0] + acc[i][1][r] * asv[1]
                         + acc[i][2][r] * asv[2] + acc[i][3][r] * asv[3];
                float vd = acc[i][0][r] * adv[0] + acc[i][1][r] * adv[1]
                         + acc[i][2][r] * adv[2] + acc[i][3][r] * adv[3];
#pragma unroll
                for (int m = 1; m < 16; m <<= 1) {
                    vs += __shfl_xor(vs, m, 16);
                    vd += __shfl_xor(vd, m, 16);
                }
                int row = m0 + wm * 64 + i * 16 + quad * 4 + r;
                if (col16 == 0 && row < M) {
                    als[row * HEADS + head] = vs;
                    ald[row * HEADS + head] = vd;
                }
            }
        }
    }
}

// ---------------------------------------------------------------------------
// Fused gather (R11 form: one wave per dst node, 4 ch/lane, 8x unroll; 8
// rows of h in flight). als/ald arrive pre-scaled by log2(e) -> bare exp2.
// ---------------------------------------------------------------------------
__global__ void gat_gather(const int* __restrict__ off,
                           const int* __restrict__ deg,
                           const int* __restrict__ csr_src,
                           const float* __restrict__ als,
                           const float* __restrict__ ald,
                           const unsigned short* __restrict__ h,
                           const float* __restrict__ bias,
                           unsigned short* __restrict__ x2, int n) {
    const int lane = threadIdx.x & 63;
    const int d = (blockIdx.x * blockDim.x + threadIdx.x) >> 6;
    if (d >= n) return;
    const int head = lane >> 4;
    const float aldh = ald[4 * d + head];
    const int start = off[d];
    const int end = start + deg[d];

    float a0 = 0.f, a1 = 0.f, a2 = 0.f, a3 = 0.f, den = 0.f;
    int j = start;
    for (; j + 8 <= end; j += 8) {
        int s[8];
#pragma unroll
        for (int u = 0; u < 8; ++u) s[u] = csr_src[j + u];
        float e[8];
#pragma unroll
        for (int u = 0; u < 8; ++u) e[u] = als[4 * s[u] + head];
        ushort4 hv[8];
#pragma unroll
        for (int u = 0; u < 8; ++u)
            hv[u] = *(const ushort4*)(h + (size_t)s[u] * FDIM + lane * 4);
#pragma unroll
        for (int u = 0; u < 8; ++u) {
            float t = e[u] + aldh;
            t = t > 0.f ? t : 0.2f * t;
            float w = fast_exp2(t);
            den += w;
            a0 += w * b2f(hv[u].x);
            a1 += w * b2f(hv[u].y);
            a2 += w * b2f(hv[u].z);
            a3 += w * b2f(hv[u].w);
        }
    }
    for (; j + 4 <= end; j += 4) {
        int s[4];
#pragma unroll
        for (int u = 0; u < 4; ++u) s[u] = csr_src[j + u];
        float e[4];
#pragma unroll
        for (int u = 0; u < 4; ++u) e[u] = als[4 * s[u] + head];
        ushort4 hv[4];
#pragma unroll
        for (int u = 0; u < 4; ++u)
            hv[u] = *(const ushort4*)(h + (size_t)s[u] * FDIM + lane * 4);
#pragma unroll
        for (int u = 0; u < 4; ++u) {
            float t = e[u] + aldh;
            t = t > 0.f ? t : 0.2f * t;
            float w = fast_exp2(t);
            den += w;
            a0 += w * b2f(hv[u].x);
            a1 += w * b2f(hv[u].y);
            a2 += w * b2f(hv[u].z);
            a3 += w * b2f(hv[u].w);
        }
    }
    for (; j < end; ++j) {
        int s = csr_src[j];
        float t = als[4 * s + head] + aldh;
        t = t > 0.f ? t : 0.2f * t;
        float w = fast_exp2(t);
        ushort4 hv = *(const ushort4*)(h + (size_t)s * FDIM + lane * 4);
        den += w;
        a0 += w * b2f(hv.x);
        a1 += w * b2f(hv.y);
        a2 += w * b2f(hv.z);
        a3 += w * b2f(hv.w);
    }
    const float inv = 1.0f / den;
    const int c = lane * 4;
    float v0 = a0 * inv + bias[c + 0];
    float v1 = a1 * inv + bias[c + 1];
    float v2 = a2 * inv + bias[c + 2];
    float v3 = a3 * inv + bias[c + 3];
    v0 = v0 > 0.f ? v0 : expm1f(v0);
    v1 = v1 > 0.f ? v1 : expm1f(v1);
    v2 = v2 > 0.f ? v2 : expm1f(v2);
    v3 = v3 > 0.f ? v3 : expm1f(v3);
    ushort4 o;
    o.x = f2b(v0); o.y = f2b(v1); o.z = f2b(v2); o.w = f2b(v3);
    *(ushort4*)(x2 + (size_t)d * FDIM + c) = o;
}

// ---------------------------------------------------------------------------
extern "C" void kernel_launch(void* const* d_in, const int* in_sizes, int n_in,
                              void* d_out, int out_size, void* d_ws, size_t ws_size,
                              hipStream_t stream) {
    const float* x   = (const float*)d_in[0];
    const int*   ei  = (const int*)d_in[1];
    const float* W1  = (const float*)d_in[3];
    const float* as1 = (const float*)d_in[4];
    const float* ad1 = (const float*)d_in[5];
    const float* b1  = (const float*)d_in[6];
    const float* W2  = (const float*)d_in[7];
    const float* as2 = (const float*)d_in[8];
    const float* ad2 = (const float*)d_in[9];
    const float* b2  = (const float*)d_in[10];
    const float* fcW = (const float*)d_in[11];
    const float* fcb = (const float*)d_in[12];
    float* out = (float*)d_out;

    const int n = in_sizes[0] / FDIM;   // 50000
    const int E = in_sizes[1] / 2;      // 800000
    const int Etot = E + n;
    const int* srcp = ei;
    const int* dstp = ei + E;
    const int nb = (n + 255) / 256;

    // -------- workspace carve (256B aligned), ~57 MB --------
    char* ws = (char*)d_ws;
    size_t off_b = 0;
    auto carve = [&](size_t bytes) -> char* {
        char* p = ws + off_b;
        off_b += (bytes + 255) & ~(size_t)255;
        return p;
    };
    unsigned short* xb = (unsigned short*)carve((size_t)n * FDIM * 2);  // also x2
    unsigned short* h  = (unsigned short*)carve((size_t)n * FDIM * 2);
    float* als  = (float*)carve((size_t)n * HEADS * 4);
    float* ald  = (float*)carve((size_t)n * HEADS * 4);
    int* deg    = (int*)carve((size_t)n * 4);
    int* offs   = (int*)carve((size_t)(n + 1) * 4);
    int* cursor = (int*)carve((size_t)n * 4);
    int* csr_src = (int*)carve((size_t)Etot * 4);
    unsigned short* Wt1  = (unsigned short*)carve(FDIM * FDIM * 2);
    unsigned short* Wt2  = (unsigned short*)carve(FDIM * FDIM * 2);
    unsigned short* fcWt = (unsigned short*)carve(64 * FDIM * 2);
    unsigned short* x2 = xb;   // alias: xb dead after layer-1 GEMM

    const int mblocks = (n + 127) / 128;
    const int nx4 = n * FDIM / 4;
    const int cvtblocks = (nx4 + 2 * FDIM * FDIM + FDIM * 64 + 255) / 256;
    const int SB = (Etot + 255) / 256;   // scatter blocks

    // -------- zero deg (stream op; capture-legal) --------
    hipMemsetAsync(deg, 0, (size_t)n * 4, stream);

    // -------- degree histogram --------
    deg_hist<<<(Etot + 255) / 256, 256, 0, stream>>>(dstp, deg, E, Etot);

    // -------- fused conversions + CSR scan (scan blocks appended) --------
    cvt_scan<<<cvtblocks + nb, 256, 0, stream>>>(
        x, xb, W1, Wt1, W2, Wt2, fcW, fcWt, deg, offs, cursor,
        nx4, n, cvtblocks);

    // -------- layer 1 GEMM + fused att coef + fused edge scatter --------
    gemm_bt_k256<128, false, true, true><<<mblocks * 2 + SB, 256, 0, stream>>>(
        xb, Wt1, h, nullptr, as1, ad1, als, ald, n, FDIM,
        srcp, dstp, cursor, csr_src, E, n);
    gat_gather<<<(n + 3) / 4, 256, 0, stream>>>(
        offs, deg, csr_src, als, ald, h, b1, x2, n);

    // -------- layer 2 --------
    gemm_bt_k256<128, false, true, false><<<mblocks * 2, 256, 0, stream>>>(
        x2, Wt2, h, nullptr, as2, ad2, als, ald, n, FDIM,
        nullptr, nullptr, nullptr, nullptr, 0, 0);
    gat_gather<<<(n + 3) / 4, 256, 0, stream>>>(
        offs, deg, csr_src, als, ald, h, b2, x2, n);

    // -------- final FC: out[n][64] = x2 @ fcW + fcb (FP32 out) --------
    gemm_bt_k256<64, true, false, false><<<mblocks, 256, 0, stream>>>(
        x2, fcWt, out, fcb, nullptr, nullptr, nullptr, nullptr, n, 64,
        nullptr, nullptr, nullptr, nullptr, 0, 0);
}